// Round 10
// baseline (443.262 us; speedup 1.0000x reference)
//
#include <hip/hip_runtime.h>
#include <stdint.h>

typedef unsigned short u16;
typedef unsigned int u32;

using bf16x8 = __attribute__((ext_vector_type(8))) short;
using bf16x4 = __attribute__((ext_vector_type(4))) short;
using f32x4  = __attribute__((ext_vector_type(4))) float;

#define GLOBAL_AS __attribute__((address_space(1)))
#define LDS_AS    __attribute__((address_space(3)))

// bank swizzle: LDS slot s of row r holds global k-group s ^ SWZ(r); readers of
// k-group q use slot q ^ SWZ(r). Spreads quad reads over all 8 4-bank windows.
#define SWZ(r) (((r) >> 1) & 3)

__device__ __forceinline__ float bf2f(u16 u) {
  union { u32 u; float f; } v; v.u = ((u32)u) << 16; return v.f;
}
__device__ __forceinline__ u16 f2bf(float f) {
  union { float f; u32 u; } v; v.f = f;
  u32 r = v.u + 0x7fffu + ((v.u >> 16) & 1u);  // round-to-nearest-even
  return (u16)(r >> 16);
}
__device__ __forceinline__ short f2bf_s(float f) { return (short)f2bf(f); }

// ---------------- fused prologue: 3 weight transposes + RMS/convert in ONE dispatch ----------------
__device__ __forceinline__ void transpose_tile_dev(
    const float* __restrict__ in, u16* __restrict__ out, int R, int C,
    int tile, int t, u16 (*tilebuf)[33]) {
  // fp32 in[R][C] -> bf16 out[C][R], one 32x32 tile.
  const int tx = t & 31, ty = t >> 5;
  const int tpr = C >> 5;            // column-tiles per input row
  const int bx = tile % tpr;
  const int by = tile / tpr;
  const int icol = bx * 32 + tx;
  const int irow0 = by * 32;
  #pragma unroll
  for (int i = ty; i < 32; i += 8)
    tilebuf[i][tx] = f2bf(in[(size_t)(irow0 + i) * C + icol]);
  __syncthreads();
  const int ocol = by * 32 + tx;
  const int orow0 = bx * 32;
  #pragma unroll
  for (int i = ty; i < 32; i += 8)
    out[(size_t)(orow0 + i) * R + ocol] = tilebuf[tx][i];
}

__device__ __forceinline__ void rms_row_dev(
    const float* __restrict__ x, float* __restrict__ s, u16* __restrict__ xb,
    int K, int row, int t, float* part) {
  // s[row]=rsqrt(mean(x^2)+eps); xb=bf16(x)  (K=4096)
  const float4* p = (const float4*)(x + (size_t)row * K);
  ushort4* q = (ushort4*)(xb + (size_t)row * K);
  float sum = 0.f;
  const int nvec = K >> 2;  // 4 fp32 per float4
  for (int i = t; i < nvec; i += 256) {
    float4 v = p[i];
    sum += v.x * v.x + v.y * v.y + v.z * v.z + v.w * v.w;
    ushort4 o;
    o.x = f2bf(v.x); o.y = f2bf(v.y); o.z = f2bf(v.z); o.w = f2bf(v.w);
    q[i] = o;
  }
  #pragma unroll
  for (int off = 32; off > 0; off >>= 1) sum += __shfl_down(sum, off, 64);
  if ((t & 63) == 0) part[t >> 6] = sum;
  __syncthreads();
  if (t == 0) {
    float tot = part[0] + part[1] + part[2] + part[3];
    s[row] = rsqrtf(tot / (float)K + 1.1920928955078125e-07f);
  }
}

// job offsets: W_u 4096 tiles | W_t 256 (->4352) | W_s 1024 (->5376) | rms 8192 rows
__global__ __launch_bounds__(256) void prologue_fused(
    const float* __restrict__ W_u, u16* __restrict__ WuT,
    const float* __restrict__ W_t, u16* __restrict__ WtT,
    const float* __restrict__ W_s, u16* __restrict__ WsT,
    const float* __restrict__ x, float* __restrict__ sscale,
    u16* __restrict__ xb) {
  __shared__ u16 tilebuf[32][33];
  __shared__ float part[4];
  const int b = blockIdx.x;
  const int t = threadIdx.x;
  if (b < 4096)      transpose_tile_dev(W_u, WuT, 4096, 1024, b, t, tilebuf);
  else if (b < 4352) transpose_tile_dev(W_t, WtT, 1024, 256, b - 4096, t, tilebuf);
  else if (b < 5376) transpose_tile_dev(W_s, WsT, 256, 4096, b - 4352, t, tilebuf);
  else               rms_row_dev(x, sscale, xb, 4096, b - 5376, t, part);
}

// ---------------- GEMM: C[M][N] = A[M][K] @ BT[N][K]^T  (+ epilogue) ----------------
// m97-style staging: __builtin_amdgcn_global_load_lds width=16 (async DMA) + XOR
// bank swizzle (conflicts measured 0). T1 XCD swizzle (grid % 8 == 0 everywhere).
// Tile geometry: block = 2x2 waves; wave tile = FM*16 x FN*16; BM=FM*32, BN=FN*32.
// R7/R9 A/B result: 128x128@2/CU = 639 TF, 64x128@4/CU = 611 TF, MfmaUtil pinned
// ~27% in both -> structure-bound (per-K-step vmcnt(0)+barrier drain), occupancy
// is NOT the limiter. GEMM1 is near this structure's ceiling for M=8192,N=1024.
// R10: GEMM1 split into two M-half dispatches (pointer offsets only; M is never
// read in the body) -> each ~57us, so any hidden dispatch >= 57us surfaces in
// the top-5 profile. Instrumentation-by-structure; numerics bit-identical.
// EPI 0: v = acc*rowscale[row] + bias[col]           (GEMM1: RMS fold)
// EPI 1: v = acc + bias[col]; strictly-upper mask    (GEMM2, N==256)
// EPI 2: v = acc + bias[col]                         (GEMM3)
template <int EPI, bool OUTF32, int FM, int FN>
__global__ __launch_bounds__(256) void gemm_bt(
    const u16* __restrict__ A, const u16* __restrict__ BT,
    const float* __restrict__ bias, const float* __restrict__ rowscale,
    void* __restrict__ Cv, int M, int N, int K) {
  static_assert((FM & 1) == 0 && (FN & 1) == 0, "64-row staging rounds");
  constexpr int BM = FM * 32;
  constexpr int BN = FN * 32;
  __shared__ u16 As[BM * 32];
  __shared__ u16 Bs[BN * 32];
  const int t = threadIdx.x;
  const int lane = t & 63;
  const int w = t >> 6;
  const int wm = (w >> 1) * FM * 16;
  const int wn = (w & 1) * FN * 16;
  const int quad = lane >> 4;
  const int lrow = lane & 15;

  // T1: XCD-aware remap of the dispatch id onto logical tile ids.
  const int orig = blockIdx.y * gridDim.x + blockIdx.x;  // HW dispatch order (x-fastest)
  const int nwg = gridDim.x * gridDim.y;
  const int cpx = nwg >> 3;                              // chunk per XCD (nwg % 8 == 0)
  const int lid = (orig & 7) * cpx + (orig >> 3);
  const int bx = lid % gridDim.x;
  const int by = lid / gridDim.x;
  const int m0 = by * BM;
  const int n0 = bx * BN;

  f32x4 acc[FM][FN] = {};

  const int srow = t >> 2;                      // staging row within 64-row round
  const int sg   = (t & 3) ^ SWZ(srow);         // global k-group feeding this LDS slot
  const size_t abase = (size_t)(m0 + srow) * K + sg * 8;
  const size_t bbase = (size_t)(n0 + srow) * K + sg * 8;

  for (int k0 = 0; k0 < K; k0 += 32) {
    __syncthreads();  // previous iteration's ds_reads complete before overwrite
    #pragma unroll
    for (int r = 0; r < FM / 2; ++r) {
      const u16* ga = A + abase + (size_t)r * 64 * K + k0;
      __builtin_amdgcn_global_load_lds((const GLOBAL_AS u32*)ga,
          (LDS_AS u32*)((u32*)As + r * 1024 + t * 4), 16, 0, 0);
    }
    #pragma unroll
    for (int r = 0; r < FN / 2; ++r) {
      const u16* gb = BT + bbase + (size_t)r * 64 * K + k0;
      __builtin_amdgcn_global_load_lds((const GLOBAL_AS u32*)gb,
          (LDS_AS u32*)((u32*)Bs + r * 1024 + t * 4), 16, 0, 0);
    }
    __syncthreads();

    bf16x8 af[FM], bv[FN];
    #pragma unroll
    for (int i = 0; i < FM; ++i)
      af[i] = *(const bf16x8*)(As + (wm + i * 16 + lrow) * 32 + (quad ^ SWZ(lrow)) * 8);
    #pragma unroll
    for (int j = 0; j < FN; ++j)
      bv[j] = *(const bf16x8*)(Bs + (wn + j * 16 + lrow) * 32 + (quad ^ SWZ(lrow)) * 8);
    #pragma unroll
    for (int i = 0; i < FM; ++i)
      #pragma unroll
      for (int j = 0; j < FN; ++j)
        acc[i][j] = __builtin_amdgcn_mfma_f32_16x16x32_bf16(af[i], bv[j], acc[i][j], 0, 0, 0);
  }

  // epilogue: C-layout col = lane&15, row = quad*4 + r
  #pragma unroll
  for (int i = 0; i < FM; ++i) {
    const int row0 = m0 + wm + i * 16 + quad * 4;
    float sc[4];
    if (EPI == 0) {
      #pragma unroll
      for (int r = 0; r < 4; ++r) sc[r] = rowscale[row0 + r];
    }
    #pragma unroll
    for (int j = 0; j < FN; ++j) {
      const int col = n0 + wn + j * 16 + lrow;
      const float bvs = bias[col];
      #pragma unroll
      for (int r = 0; r < 4; ++r) {
        float v = acc[i][j][r];
        if (EPI == 0) v = v * sc[r] + bvs;
        else v += bvs;
        if (EPI == 1) {
          const int cc = col & 255;  // N==256 here: flat idx = i16*16 + j16
          if ((cc & 15) <= (cc >> 4)) v = 0.f;  // keep strictly upper (j16 > i16)
        }
        const size_t idx = (size_t)(row0 + r) * N + col;
        if (OUTF32) ((float*)Cv)[idx] = v;
        else        ((u16*)Cv)[idx] = f2bf(v);
      }
    }
  }
}

// ---------------- per-row 16x16 expm via Taylor (exact: M nilpotent, M^16=0) ----------------
// One wave per row (4 rows/block). Left recurrence: term_k = (M * term_{k-1}) / k.
// Register-resident inner loop; see R0 notes. Primary: mfma_f32_16x16x16 (K=16,
// B-layout == C/D-layout -> free handoff). Fallback: 16x16x32 + 4 __shfl's.
#define HAS_MFMA16X16X16 __has_builtin(__builtin_amdgcn_mfma_f32_16x16x16bf16_1k)

__global__ __launch_bounds__(256) void expm_taylor(
    const u16* __restrict__ Mi, u16* __restrict__ Eo) {
  __shared__ u16 mbuf[4][256];
  const int t = threadIdx.x;
  const int w = t >> 6;
  const int lane = t & 63;
  const int q = lane >> 4;
  const int c = lane & 15;
  const size_t row = (size_t)blockIdx.x * 4 + w;

  *(uint2*)&mbuf[w][lane * 4] = *(const uint2*)(Mi + row * 256 + lane * 4);
  __syncthreads();  // once: make mbuf visible across lanes (cheap, outside loop)

  const u16* mb = mbuf[w];

  // res = I + M  (C-layout: entry (q*4+r, c))
  float res[4];
  #pragma unroll
  for (int r = 0; r < 4; ++r) {
    const int rw = q * 4 + r;
    res[r] = (rw == c ? 1.f : 0.f) + bf2f(mb[rw * 16 + c]);
  }

#if HAS_MFMA16X16X16
  bf16x4 afrM, bfr;
  #pragma unroll
  for (int jj = 0; jj < 4; ++jj) {
    afrM[jj] = (short)mb[c * 16 + q * 4 + jj];        // A[m=c][k=q*4+jj] = M[c][k]
    bfr[jj]  = (short)mb[(q * 4 + jj) * 16 + c];      // B[k][n=c] = term[k][c], term=M
  }
  #pragma unroll
  for (int k = 2; k <= 15; ++k) {
    const f32x4 z = {0.f, 0.f, 0.f, 0.f};
    f32x4 P = __builtin_amdgcn_mfma_f32_16x16x16bf16_1k(afrM, bfr, z, 0, 0, 0);
    const float inv = 1.0f / (float)k;
    #pragma unroll
    for (int r = 0; r < 4; ++r) {
      const float tv = P[r] * inv;
      res[r] += tv;
      bfr[r] = f2bf_s(tv);   // C(row=q*4+r,col=c) == B(k=q*4+r,n=c): free handoff
    }
  }
#else
  const bf16x8 z8 = {0, 0, 0, 0, 0, 0, 0, 0};
  bf16x8 afrM = z8;  // A[m=c][k=q*8+jj], zero-padded K 16->32 (q>=2)
  bf16x8 bfr  = z8;  // B[k=q*8+jj][n=c] = term[k][c], init term = M
  if (q < 2) {
    #pragma unroll
    for (int jj = 0; jj < 8; ++jj) {
      afrM[jj] = (short)mb[c * 16 + q * 8 + jj];
      bfr[jj]  = (short)mb[(q * 8 + jj) * 16 + c];
    }
  }
  const int qq = q & 1;
  const int sA = qq * 32 + c;       // lane holding term rows 8q..8q+3 (col c)
  const int sB = sA + 16;           // lane holding term rows 8q+4..8q+7
  #pragma unroll
  for (int k = 2; k <= 15; ++k) {
    const f32x4 z = {0.f, 0.f, 0.f, 0.f};
    f32x4 P = __builtin_amdgcn_mfma_f32_16x16x32_bf16(afrM, bfr, z, 0, 0, 0);
    const float inv = 1.0f / (float)k;
    float tv[4];
    #pragma unroll
    for (int r = 0; r < 4; ++r) { tv[r] = P[r] * inv; res[r] += tv[r]; }
    if (k < 15) {
      const u32 w0 = ((u32)f2bf(tv[0])) | (((u32)f2bf(tv[1])) << 16);
      const u32 w1 = ((u32)f2bf(tv[2])) | (((u32)f2bf(tv[3])) << 16);
      u32 a0 = (u32)__shfl((int)w0, sA, 64);
      u32 a1 = (u32)__shfl((int)w1, sA, 64);
      u32 a2 = (u32)__shfl((int)w0, sB, 64);
      u32 a3 = (u32)__shfl((int)w1, sB, 64);
      if (q >= 2) { a0 = a1 = a2 = a3 = 0; }  // K-pad rows stay zero
      union { u32 u[4]; bf16x8 v; } bu;
      bu.u[0] = a0; bu.u[1] = a1; bu.u[2] = a2; bu.u[3] = a3;
      bfr = bu.v;
    }
  }
#endif

  #pragma unroll
  for (int r = 0; r < 4; ++r)
    Eo[row * 256 + (size_t)(q * 4 + r) * 16 + c] = f2bf(res[r]);
}

extern "C" void kernel_launch(void* const* d_in, const int* in_sizes, int n_in,
                              void* d_out, int out_size, void* d_ws, size_t ws_size,
                              hipStream_t stream) {
  (void)in_sizes; (void)n_in; (void)out_size; (void)ws_size;
  // Inputs are FLOAT32 per the reference (jnp.float32).
  const float* x   = (const float*)d_in[0];
  const float* W_u = (const float*)d_in[1];
  const float* b_u = (const float*)d_in[2];
  const float* W_t = (const float*)d_in[3];
  const float* b_t = (const float*)d_in[4];
  const float* W_s = (const float*)d_in[5];
  const float* b_s = (const float*)d_in[6];
  float* out = (float*)d_out;  // output fp32 (reference output dtype)

  // d_out is 128 MiB (8192*4096 fp32) — dead until GEMM3; use it as scratch:
  //   xb     bf16[8192][4096] at +0      (64 MiB)
  //   latent bf16[8192][1024] at +64MiB  (16 MiB)
  //   mmat   bf16[8192][256]  at +80MiB  (4 MiB)
  u16* xb     = (u16*)d_out;
  u16* latent = xb + (size_t)8192 * 4096;
  u16* mmat   = latent + (size_t)8192 * 1024;

  char* ws = (char*)d_ws;  // ~14.5 MiB total
  size_t off = 0;
  float* sscale = (float*)(ws + off); off += (size_t)8192 * sizeof(float);
  u16* WuT  = (u16*)(ws + off); off += (size_t)1024 * 4096 * 2;  // 8 MiB
  u16* WtT  = (u16*)(ws + off); off += (size_t)256 * 1024 * 2;   // 0.5 MiB
  u16* WsT  = (u16*)(ws + off); off += (size_t)4096 * 256 * 2;   // 2 MiB
  u16* eexp = (u16*)(ws + off); off += (size_t)8192 * 256 * 2;   // 4 MiB

  // fused prologue: W_u/W_t/W_s transposes + RMS scales + x->bf16  (one dispatch)
  // blocks: 4096 (WuT) + 256 (WtT) + 1024 (WsT) + 8192 (rms rows) = 13568
  prologue_fused<<<13568, 256, 0, stream>>>(W_u, WuT, W_t, WtT, W_s, WsT,
                                            x, sscale, xb);

  // latent = diag(s)*(xb @ W_u) + b_u   [8192,1024] bf16
  // R10 instrumentation: two M-half dispatches (4096 rows each, pointer offsets
  // only -> bit-identical numerics). Each ~57us so hidden dispatches >=57us
  // surface in the top-5 profile.
  {
    const size_t MH = 4096;
    gemm_bt<0, false, 2, 4><<<dim3(1024 / 128, MH / 64), 256, 0, stream>>>(
        xb, WuT, b_u, sscale, latent, (int)MH, 1024, 4096);
    gemm_bt<0, false, 2, 4><<<dim3(1024 / 128, MH / 64), 256, 0, stream>>>(
        xb + MH * 4096, WuT, b_u, sscale + MH, latent + MH * 1024, (int)MH, 1024, 4096);
  }
  // mmat = mask(latent @ W_t + b_t)     [8192,256] bf16  (64x64 tile, 512 blocks)
  gemm_bt<1, false, 2, 2><<<dim3(256 / 64, 8192 / 64), 256, 0, stream>>>(
      latent, WtT, b_t, nullptr, mmat, 8192, 256, 1024);
  // eexp = expm(mmat)                    [8192,256] bf16 (ws)
  expm_taylor<<<8192 / 4, 256, 0, stream>>>(mmat, eexp);
  // out = eexp @ W_s + b_s               [8192,4096] fp32 (overwrites scratch, now dead)
  gemm_bt<2, true, 4, 4><<<dim3(4096 / 128, 8192 / 128), 256, 0, stream>>>(
      eexp, WsT, b_s, nullptr, out, 8192, 4096, 256);
}

// Round 12
// 392.324 us; speedup vs baseline: 1.1298x; 1.1298x over previous
//
#include <hip/hip_runtime.h>
#include <stdint.h>

typedef unsigned short u16;
typedef unsigned int u32;

using bf16x8 = __attribute__((ext_vector_type(8))) short;
using bf16x4 = __attribute__((ext_vector_type(4))) short;
using f32x4  = __attribute__((ext_vector_type(4))) float;

#define GLOBAL_AS __attribute__((address_space(1)))
#define LDS_AS    __attribute__((address_space(3)))

// bank swizzle: LDS slot s of row r holds global k-group s ^ SWZ(r); readers of
// k-group q use slot q ^ SWZ(r). Spreads quad reads over all 8 4-bank windows.
#define SWZ(r) (((r) >> 1) & 3)

__device__ __forceinline__ float bf2f(u16 u) {
  union { u32 u; float f; } v; v.u = ((u32)u) << 16; return v.f;
}
__device__ __forceinline__ u16 f2bf(float f) {
  union { float f; u32 u; } v; v.f = f;
  u32 r = v.u + 0x7fffu + ((v.u >> 16) & 1u);  // round-to-nearest-even
  return (u16)(r >> 16);
}
__device__ __forceinline__ short f2bf_s(float f) { return (short)f2bf(f); }

// ---------------- fused prologue: 3 weight transposes + RMS/convert in ONE dispatch ----------------
__device__ __forceinline__ void transpose_tile_dev(
    const float* __restrict__ in, u16* __restrict__ out, int R, int C,
    int tile, int t, u16 (*tilebuf)[33]) {
  // fp32 in[R][C] -> bf16 out[C][R], one 32x32 tile.
  const int tx = t & 31, ty = t >> 5;
  const int tpr = C >> 5;            // column-tiles per input row
  const int bx = tile % tpr;
  const int by = tile / tpr;
  const int icol = bx * 32 + tx;
  const int irow0 = by * 32;
  #pragma unroll
  for (int i = ty; i < 32; i += 8)
    tilebuf[i][tx] = f2bf(in[(size_t)(irow0 + i) * C + icol]);
  __syncthreads();
  const int ocol = by * 32 + tx;
  const int orow0 = bx * 32;
  #pragma unroll
  for (int i = ty; i < 32; i += 8)
    out[(size_t)(orow0 + i) * R + ocol] = tilebuf[tx][i];
}

__device__ __forceinline__ void rms_row_dev(
    const float* __restrict__ x, float* __restrict__ s, u16* __restrict__ xb,
    int K, int row, int t, float* part) {
  // s[row]=rsqrt(mean(x^2)+eps); xb=bf16(x)  (K=4096)
  const float4* p = (const float4*)(x + (size_t)row * K);
  ushort4* q = (ushort4*)(xb + (size_t)row * K);
  float sum = 0.f;
  const int nvec = K >> 2;  // 4 fp32 per float4
  for (int i = t; i < nvec; i += 256) {
    float4 v = p[i];
    sum += v.x * v.x + v.y * v.y + v.z * v.z + v.w * v.w;
    ushort4 o;
    o.x = f2bf(v.x); o.y = f2bf(v.y); o.z = f2bf(v.z); o.w = f2bf(v.w);
    q[i] = o;
  }
  #pragma unroll
  for (int off = 32; off > 0; off >>= 1) sum += __shfl_down(sum, off, 64);
  if ((t & 63) == 0) part[t >> 6] = sum;
  __syncthreads();
  if (t == 0) {
    float tot = part[0] + part[1] + part[2] + part[3];
    s[row] = rsqrtf(tot / (float)K + 1.1920928955078125e-07f);
  }
}

// job offsets: W_u 4096 tiles | W_t 256 (->4352) | W_s 1024 (->5376) | rms 8192 rows
__global__ __launch_bounds__(256) void prologue_fused(
    const float* __restrict__ W_u, u16* __restrict__ WuT,
    const float* __restrict__ W_t, u16* __restrict__ WtT,
    const float* __restrict__ W_s, u16* __restrict__ WsT,
    const float* __restrict__ x, float* __restrict__ sscale,
    u16* __restrict__ xb) {
  __shared__ u16 tilebuf[32][33];
  __shared__ float part[4];
  const int b = blockIdx.x;
  const int t = threadIdx.x;
  if (b < 4096)      transpose_tile_dev(W_u, WuT, 4096, 1024, b, t, tilebuf);
  else if (b < 4352) transpose_tile_dev(W_t, WtT, 1024, 256, b - 4096, t, tilebuf);
  else if (b < 5376) transpose_tile_dev(W_s, WsT, 256, 4096, b - 4352, t, tilebuf);
  else               rms_row_dev(x, sscale, xb, 4096, b - 5376, t, part);
}

// ---------------- GEMM: C[M][N] = A[M][K] @ BT[N][K]^T  (+ epilogue) ----------------
// m97-style staging (global_load_lds width=16) + XOR bank swizzle (measured 0
// conflicts) + T1 XCD swizzle (grid % 8 == 0 at every call site).
// R11: single-barrier DOUBLE-BUFFERED K-loop. Old: sync; issue DMAs; sync(drain);
// compute -- full HBM latency exposed each K-step (MfmaUtil pinned 27% across
// 2 and 4 blocks/CU, R7/R9). New: stage tile t+1 right after the sync, compute
// tile t, let the NEXT iteration's __syncthreads do the drain (hipcc emits
// s_waitcnt vmcnt(0) lgkmcnt(0) before s_barrier -- loads get the whole
// ds_read+MFMA phase in flight). Every producer->consumer edge crosses a
// barrier: staged(t)->read after t+1's sync; read(t)->overwrite after t+1's
// sync. One barrier per K-step instead of two.
// Tile history: 128x128@2/CU = 107.5us (R7) beat 64x128@4/CU = 112.5us (R9);
// R10 M-split cost +33us (reverted). GEMM1/GEMM3 use 128x128; GEMM2 64x64.
// EPI 0: v = acc*rowscale[row] + bias[col]           (GEMM1: RMS fold)
// EPI 1: v = acc + bias[col]; strictly-upper mask    (GEMM2, N==256)
// EPI 2: v = acc + bias[col]                         (GEMM3)
template <int EPI, bool OUTF32, int FM, int FN>
__global__ __launch_bounds__(256) void gemm_bt(
    const u16* __restrict__ A, const u16* __restrict__ BT,
    const float* __restrict__ bias, const float* __restrict__ rowscale,
    void* __restrict__ Cv, int M, int N, int K) {
  static_assert((FM & 1) == 0 && (FN & 1) == 0, "64-row staging rounds");
  constexpr int BM = FM * 32;
  constexpr int BN = FN * 32;
  __shared__ u16 As[2][BM * 32];
  __shared__ u16 Bs[2][BN * 32];
  const int t = threadIdx.x;
  const int lane = t & 63;
  const int w = t >> 6;
  const int wm = (w >> 1) * FM * 16;
  const int wn = (w & 1) * FN * 16;
  const int quad = lane >> 4;
  const int lrow = lane & 15;

  // T1: XCD-aware remap of the dispatch id onto logical tile ids.
  const int orig = blockIdx.y * gridDim.x + blockIdx.x;  // HW dispatch order (x-fastest)
  const int nwg = gridDim.x * gridDim.y;
  const int cpx = nwg >> 3;                              // chunk per XCD (nwg % 8 == 0)
  const int lid = (orig & 7) * cpx + (orig >> 3);
  const int bx = lid % gridDim.x;
  const int by = lid / gridDim.x;
  const int m0 = by * BM;
  const int n0 = bx * BN;

  f32x4 acc[FM][FN] = {};

  const int srow = t >> 2;                      // staging row within 64-row round
  const int sg   = (t & 3) ^ SWZ(srow);         // global k-group feeding this LDS slot
  const size_t abase = (size_t)(m0 + srow) * K + sg * 8;
  const size_t bbase = (size_t)(n0 + srow) * K + sg * 8;

  auto STAGE = [&](int buf, int k0) {
    #pragma unroll
    for (int r = 0; r < FM / 2; ++r) {
      const u16* ga = A + abase + (size_t)r * 64 * K + k0;
      __builtin_amdgcn_global_load_lds((const GLOBAL_AS u32*)ga,
          (LDS_AS u32*)((u32*)As[buf] + r * 1024 + t * 4), 16, 0, 0);
    }
    #pragma unroll
    for (int r = 0; r < FN / 2; ++r) {
      const u16* gb = BT + bbase + (size_t)r * 64 * K + k0;
      __builtin_amdgcn_global_load_lds((const GLOBAL_AS u32*)gb,
          (LDS_AS u32*)((u32*)Bs[buf] + r * 1024 + t * 4), 16, 0, 0);
    }
  };

  STAGE(0, 0);          // prologue: first tile in flight; drained by first sync
  int p = 0;
  for (int k0 = 0; k0 < K; k0 += 32) {
    __syncthreads();    // drains vmcnt+lgkmcnt: staged(t) ready, reads(t-1) done
    if (k0 + 32 < K) STAGE(p ^ 1, k0 + 32);  // uniform branch, no barrier inside

    bf16x8 af[FM], bv[FN];
    #pragma unroll
    for (int i = 0; i < FM; ++i)
      af[i] = *(const bf16x8*)(As[p] + (wm + i * 16 + lrow) * 32 + (quad ^ SWZ(lrow)) * 8);
    #pragma unroll
    for (int j = 0; j < FN; ++j)
      bv[j] = *(const bf16x8*)(Bs[p] + (wn + j * 16 + lrow) * 32 + (quad ^ SWZ(lrow)) * 8);
    #pragma unroll
    for (int i = 0; i < FM; ++i)
      #pragma unroll
      for (int j = 0; j < FN; ++j)
        acc[i][j] = __builtin_amdgcn_mfma_f32_16x16x32_bf16(af[i], bv[j], acc[i][j], 0, 0, 0);
    p ^= 1;
  }

  // epilogue: C-layout col = lane&15, row = quad*4 + r
  #pragma unroll
  for (int i = 0; i < FM; ++i) {
    const int row0 = m0 + wm + i * 16 + quad * 4;
    float sc[4];
    if (EPI == 0) {
      #pragma unroll
      for (int r = 0; r < 4; ++r) sc[r] = rowscale[row0 + r];
    }
    #pragma unroll
    for (int j = 0; j < FN; ++j) {
      const int col = n0 + wn + j * 16 + lrow;
      const float bvs = bias[col];
      #pragma unroll
      for (int r = 0; r < 4; ++r) {
        float v = acc[i][j][r];
        if (EPI == 0) v = v * sc[r] + bvs;
        else v += bvs;
        if (EPI == 1) {
          const int cc = col & 255;  // N==256 here: flat idx = i16*16 + j16
          if ((cc & 15) <= (cc >> 4)) v = 0.f;  // keep strictly upper (j16 > i16)
        }
        const size_t idx = (size_t)(row0 + r) * N + col;
        if (OUTF32) ((float*)Cv)[idx] = v;
        else        ((u16*)Cv)[idx] = f2bf(v);
      }
    }
  }
}

// ---------------- per-row 16x16 expm via Taylor (exact: M nilpotent, M^16=0) ----------------
// One wave per row (4 rows/block). Left recurrence: term_k = (M * term_{k-1}) / k.
// Register-resident inner loop; see R0 notes. Primary: mfma_f32_16x16x16 (K=16,
// B-layout == C/D-layout -> free handoff). Fallback: 16x16x32 + 4 __shfl's.
#define HAS_MFMA16X16X16 __has_builtin(__builtin_amdgcn_mfma_f32_16x16x16bf16_1k)

__global__ __launch_bounds__(256) void expm_taylor(
    const u16* __restrict__ Mi, u16* __restrict__ Eo) {
  __shared__ u16 mbuf[4][256];
  const int t = threadIdx.x;
  const int w = t >> 6;
  const int lane = t & 63;
  const int q = lane >> 4;
  const int c = lane & 15;
  const size_t row = (size_t)blockIdx.x * 4 + w;

  *(uint2*)&mbuf[w][lane * 4] = *(const uint2*)(Mi + row * 256 + lane * 4);
  __syncthreads();  // once: make mbuf visible across lanes (cheap, outside loop)

  const u16* mb = mbuf[w];

  // res = I + M  (C-layout: entry (q*4+r, c))
  float res[4];
  #pragma unroll
  for (int r = 0; r < 4; ++r) {
    const int rw = q * 4 + r;
    res[r] = (rw == c ? 1.f : 0.f) + bf2f(mb[rw * 16 + c]);
  }

#if HAS_MFMA16X16X16
  bf16x4 afrM, bfr;
  #pragma unroll
  for (int jj = 0; jj < 4; ++jj) {
    afrM[jj] = (short)mb[c * 16 + q * 4 + jj];        // A[m=c][k=q*4+jj] = M[c][k]
    bfr[jj]  = (short)mb[(q * 4 + jj) * 16 + c];      // B[k][n=c] = term[k][c], term=M
  }
  #pragma unroll
  for (int k = 2; k <= 15; ++k) {
    const f32x4 z = {0.f, 0.f, 0.f, 0.f};
    f32x4 P = __builtin_amdgcn_mfma_f32_16x16x16bf16_1k(afrM, bfr, z, 0, 0, 0);
    const float inv = 1.0f / (float)k;
    #pragma unroll
    for (int r = 0; r < 4; ++r) {
      const float tv = P[r] * inv;
      res[r] += tv;
      bfr[r] = f2bf_s(tv);   // C(row=q*4+r,col=c) == B(k=q*4+r,n=c): free handoff
    }
  }
#else
  const bf16x8 z8 = {0, 0, 0, 0, 0, 0, 0, 0};
  bf16x8 afrM = z8;  // A[m=c][k=q*8+jj], zero-padded K 16->32 (q>=2)
  bf16x8 bfr  = z8;  // B[k=q*8+jj][n=c] = term[k][c], init term = M
  if (q < 2) {
    #pragma unroll
    for (int jj = 0; jj < 8; ++jj) {
      afrM[jj] = (short)mb[c * 16 + q * 8 + jj];
      bfr[jj]  = (short)mb[(q * 8 + jj) * 16 + c];
    }
  }
  const int qq = q & 1;
  const int sA = qq * 32 + c;       // lane holding term rows 8q..8q+3 (col c)
  const int sB = sA + 16;           // lane holding term rows 8q+4..8q+7
  #pragma unroll
  for (int k = 2; k <= 15; ++k) {
    const f32x4 z = {0.f, 0.f, 0.f, 0.f};
    f32x4 P = __builtin_amdgcn_mfma_f32_16x16x32_bf16(afrM, bfr, z, 0, 0, 0);
    const float inv = 1.0f / (float)k;
    float tv[4];
    #pragma unroll
    for (int r = 0; r < 4; ++r) { tv[r] = P[r] * inv; res[r] += tv[r]; }
    if (k < 15) {
      const u32 w0 = ((u32)f2bf(tv[0])) | (((u32)f2bf(tv[1])) << 16);
      const u32 w1 = ((u32)f2bf(tv[2])) | (((u32)f2bf(tv[3])) << 16);
      u32 a0 = (u32)__shfl((int)w0, sA, 64);
      u32 a1 = (u32)__shfl((int)w1, sA, 64);
      u32 a2 = (u32)__shfl((int)w0, sB, 64);
      u32 a3 = (u32)__shfl((int)w1, sB, 64);
      if (q >= 2) { a0 = a1 = a2 = a3 = 0; }  // K-pad rows stay zero
      union { u32 u[4]; bf16x8 v; } bu;
      bu.u[0] = a0; bu.u[1] = a1; bu.u[2] = a2; bu.u[3] = a3;
      bfr = bu.v;
    }
  }
#endif

  #pragma unroll
  for (int r = 0; r < 4; ++r)
    Eo[row * 256 + (size_t)(q * 4 + r) * 16 + c] = f2bf(res[r]);
}

extern "C" void kernel_launch(void* const* d_in, const int* in_sizes, int n_in,
                              void* d_out, int out_size, void* d_ws, size_t ws_size,
                              hipStream_t stream) {
  (void)in_sizes; (void)n_in; (void)out_size; (void)ws_size;
  // Inputs are FLOAT32 per the reference (jnp.float32).
  const float* x   = (const float*)d_in[0];
  const float* W_u = (const float*)d_in[1];
  const float* b_u = (const float*)d_in[2];
  const float* W_t = (const float*)d_in[3];
  const float* b_t = (const float*)d_in[4];
  const float* W_s = (const float*)d_in[5];
  const float* b_s = (const float*)d_in[6];
  float* out = (float*)d_out;  // output fp32 (reference output dtype)

  // d_out is 128 MiB (8192*4096 fp32) — dead until GEMM3; use it as scratch:
  //   xb     bf16[8192][4096] at +0      (64 MiB)
  //   latent bf16[8192][1024] at +64MiB  (16 MiB)
  //   mmat   bf16[8192][256]  at +80MiB  (4 MiB)
  u16* xb     = (u16*)d_out;
  u16* latent = xb + (size_t)8192 * 4096;
  u16* mmat   = latent + (size_t)8192 * 1024;

  char* ws = (char*)d_ws;  // ~14.5 MiB total
  size_t off = 0;
  float* sscale = (float*)(ws + off); off += (size_t)8192 * sizeof(float);
  u16* WuT  = (u16*)(ws + off); off += (size_t)1024 * 4096 * 2;  // 8 MiB
  u16* WtT  = (u16*)(ws + off); off += (size_t)256 * 1024 * 2;   // 0.5 MiB
  u16* WsT  = (u16*)(ws + off); off += (size_t)4096 * 256 * 2;   // 2 MiB
  u16* eexp = (u16*)(ws + off); off += (size_t)8192 * 256 * 2;   // 4 MiB

  // fused prologue: W_u/W_t/W_s transposes + RMS scales + x->bf16  (one dispatch)
  // blocks: 4096 (WuT) + 256 (WtT) + 1024 (WsT) + 8192 (rms rows) = 13568
  prologue_fused<<<13568, 256, 0, stream>>>(W_u, WuT, W_t, WtT, W_s, WsT,
                                            x, sscale, xb);

  // latent = diag(s)*(xb @ W_u) + b_u   [8192,1024] bf16
  // single dispatch, 128x128 tile (R7 measured-best), dbuf K-loop
  gemm_bt<0, false, 4, 4><<<dim3(1024 / 128, 8192 / 128), 256, 0, stream>>>(
      xb, WuT, b_u, sscale, latent, 8192, 1024, 4096);
  // mmat = mask(latent @ W_t + b_t)     [8192,256] bf16  (64x64 tile, 512 blocks)
  gemm_bt<1, false, 2, 2><<<dim3(256 / 64, 8192 / 64), 256, 0, stream>>>(
      latent, WtT, b_t, nullptr, mmat, 8192, 256, 1024);
  // eexp = expm(mmat)                    [8192,256] bf16 (ws)
  expm_taylor<<<8192 / 4, 256, 0, stream>>>(mmat, eexp);
  // out = eexp @ W_s + b_s               [8192,4096] fp32 (overwrites scratch, now dead)
  gemm_bt<2, true, 4, 4><<<dim3(4096 / 128, 8192 / 128), 256, 0, stream>>>(
      eexp, WsT, b_s, nullptr, out, 8192, 4096, 256);
}

// Round 13
// 373.356 us; speedup vs baseline: 1.1872x; 1.0508x over previous
//
#include <hip/hip_runtime.h>
#include <stdint.h>

typedef unsigned short u16;
typedef unsigned int u32;

using bf16x8 = __attribute__((ext_vector_type(8))) short;
using bf16x4 = __attribute__((ext_vector_type(4))) short;
using f32x4  = __attribute__((ext_vector_type(4))) float;

#define GLOBAL_AS __attribute__((address_space(1)))
#define LDS_AS    __attribute__((address_space(3)))

// BK=32 bank swizzle (4 slots/row of 16B): slot s of row r holds k-group s^SWZ(r).
#define SWZ(r) (((r) >> 1) & 3)

__device__ __forceinline__ float bf2f(u16 u) {
  union { u32 u; float f; } v; v.u = ((u32)u) << 16; return v.f;
}
__device__ __forceinline__ u16 f2bf(float f) {
  union { float f; u32 u; } v; v.f = f;
  u32 r = v.u + 0x7fffu + ((v.u >> 16) & 1u);  // round-to-nearest-even
  return (u16)(r >> 16);
}
__device__ __forceinline__ short f2bf_s(float f) { return (short)f2bf(f); }

// ---------------- fused prologue: 3 weight transposes + RMS/convert in ONE dispatch ----------------
__device__ __forceinline__ void transpose_tile_dev(
    const float* __restrict__ in, u16* __restrict__ out, int R, int C,
    int tile, int t, u16 (*tilebuf)[33]) {
  // fp32 in[R][C] -> bf16 out[C][R], one 32x32 tile.
  const int tx = t & 31, ty = t >> 5;
  const int tpr = C >> 5;            // column-tiles per input row
  const int bx = tile % tpr;
  const int by = tile / tpr;
  const int icol = bx * 32 + tx;
  const int irow0 = by * 32;
  #pragma unroll
  for (int i = ty; i < 32; i += 8)
    tilebuf[i][tx] = f2bf(in[(size_t)(irow0 + i) * C + icol]);
  __syncthreads();
  const int ocol = by * 32 + tx;
  const int orow0 = bx * 32;
  #pragma unroll
  for (int i = ty; i < 32; i += 8)
    out[(size_t)(orow0 + i) * R + ocol] = tilebuf[tx][i];
}

__device__ __forceinline__ void rms_row_dev(
    const float* __restrict__ x, float* __restrict__ s, u16* __restrict__ xb,
    int K, int row, int t, float* part) {
  // s[row]=rsqrt(mean(x^2)+eps); xb=bf16(x)  (K=4096)
  const float4* p = (const float4*)(x + (size_t)row * K);
  ushort4* q = (ushort4*)(xb + (size_t)row * K);
  float sum = 0.f;
  const int nvec = K >> 2;  // 4 fp32 per float4
  for (int i = t; i < nvec; i += 256) {
    float4 v = p[i];
    sum += v.x * v.x + v.y * v.y + v.z * v.z + v.w * v.w;
    ushort4 o;
    o.x = f2bf(v.x); o.y = f2bf(v.y); o.z = f2bf(v.z); o.w = f2bf(v.w);
    q[i] = o;
  }
  #pragma unroll
  for (int off = 32; off > 0; off >>= 1) sum += __shfl_down(sum, off, 64);
  if ((t & 63) == 0) part[t >> 6] = sum;
  __syncthreads();
  if (t == 0) {
    float tot = part[0] + part[1] + part[2] + part[3];
    s[row] = rsqrtf(tot / (float)K + 1.1920928955078125e-07f);
  }
}

// job offsets: W_u 4096 tiles | W_t 256 (->4352) | W_s 1024 (->5376) | rms 8192 rows
__global__ __launch_bounds__(256) void prologue_fused(
    const float* __restrict__ W_u, u16* __restrict__ WuT,
    const float* __restrict__ W_t, u16* __restrict__ WtT,
    const float* __restrict__ W_s, u16* __restrict__ WsT,
    const float* __restrict__ x, float* __restrict__ sscale,
    u16* __restrict__ xb) {
  __shared__ u16 tilebuf[32][33];
  __shared__ float part[4];
  const int b = blockIdx.x;
  const int t = threadIdx.x;
  if (b < 4096)      transpose_tile_dev(W_u, WuT, 4096, 1024, b, t, tilebuf);
  else if (b < 4352) transpose_tile_dev(W_t, WtT, 1024, 256, b - 4096, t, tilebuf);
  else if (b < 5376) transpose_tile_dev(W_s, WsT, 256, 4096, b - 4352, t, tilebuf);
  else               rms_row_dev(x, sscale, xb, 4096, b - 5376, t, part);
}

// ---------------- GEMM: C[M][N] = A[M][K] @ BT[N][K]^T  (+ epilogue) ----------------
// global_load_lds width=16 staging + XOR bank swizzle + T1 XCD swizzle (grid%8==0)
// + R11 single-barrier dbuf (verified R12: GEMM1 107.5->97.5us, VALUBusy 40->17%).
// R13: BKT=64 for GEMM1/GEMM2. R12 counters: MfmaUtil 29%, VALU 17% -> ~50% of
// cycles are barrier-drain waits. Per-barrier compute at BK=32 is ~256 matrix
// cycles/SIMD (2 waves) vs ~500-900cy HBM latency for the prefetched tile.
// BK=64 doubles compute per drain (32 MFMA/wave) and halves barrier count.
// LDS 64 KiB (dbuf) -> still 2 blocks/CU; GEMM1/2 are grid-limited to 2 anyway.
// GEMM3 KEEPS BKT=32: it runs 4 blocks/CU (32 KiB LDS); 64 KiB would halve that.
// BKT=64 layout: row = 64 u16 = 128B = exact bank period; 8 slots of 16B;
// staging slot t&7 <- global k-group (t&7)^(row&7); read slot (s*4+quad)^(lrow&7)
// (row == lrow mod 8). 8 lanes/slot, evenly spread -> expect ~0 conflicts.
// EPI 0: v = acc*rowscale[row] + bias[col]           (GEMM1: RMS fold)
// EPI 1: v = acc + bias[col]; strictly-upper mask    (GEMM2, N==256)
// EPI 2: v = acc + bias[col]                         (GEMM3)
template <int EPI, bool OUTF32, int FM, int FN, int BKT>
__global__ __launch_bounds__(256) void gemm_bt(
    const u16* __restrict__ A, const u16* __restrict__ BT,
    const float* __restrict__ bias, const float* __restrict__ rowscale,
    void* __restrict__ Cv, int M, int N, int K) {
  static_assert((FM & 1) == 0 && (FN & 1) == 0, "staging round geometry");
  static_assert(BKT == 32 || BKT == 64, "BKT");
  constexpr int BM = FM * 32;
  constexpr int BN = FN * 32;
  __shared__ u16 As[2][BM * BKT];
  __shared__ u16 Bs[2][BN * BKT];
  const int t = threadIdx.x;
  const int lane = t & 63;
  const int w = t >> 6;
  const int wm = (w >> 1) * FM * 16;
  const int wn = (w & 1) * FN * 16;
  const int quad = lane >> 4;
  const int lrow = lane & 15;

  // T1: XCD-aware remap of the dispatch id onto logical tile ids.
  const int orig = blockIdx.y * gridDim.x + blockIdx.x;  // HW dispatch order (x-fastest)
  const int nwg = gridDim.x * gridDim.y;
  const int cpx = nwg >> 3;                              // chunk per XCD (nwg % 8 == 0)
  const int lid = (orig & 7) * cpx + (orig >> 3);
  const int bx = lid % gridDim.x;
  const int by = lid / gridDim.x;
  const int m0 = by * BM;
  const int n0 = bx * BN;

  f32x4 acc[FM][FN] = {};

  // Staging geometry. Both variants advance LDS by 1024 u32 per round.
  //   BKT=32: round = 64 rows x 32 u16; srow=t>>2, 4 slots, sg=(t&3)^SWZ(srow)
  //   BKT=64: round = 32 rows x 64 u16; srow=t>>3, 8 slots, sg=(t&7)^(srow&7)
  constexpr int AR = (BKT == 64) ? FM : FM / 2;   // A staging rounds
  constexpr int BR = (BKT == 64) ? FN : FN / 2;   // B staging rounds
  constexpr int RROWS = (BKT == 64) ? 32 : 64;    // rows per round
  const int srow = (BKT == 64) ? (t >> 3) : (t >> 2);
  const int sg   = (BKT == 64) ? ((t & 7) ^ (srow & 7)) : ((t & 3) ^ SWZ(srow));
  const size_t abase = (size_t)(m0 + srow) * K + sg * 8;
  const size_t bbase = (size_t)(n0 + srow) * K + sg * 8;

  auto STAGE = [&](int buf, int k0) {
    #pragma unroll
    for (int r = 0; r < AR; ++r) {
      const u16* ga = A + abase + (size_t)r * RROWS * K + k0;
      __builtin_amdgcn_global_load_lds((const GLOBAL_AS u32*)ga,
          (LDS_AS u32*)((u32*)As[buf] + r * 1024 + t * 4), 16, 0, 0);
    }
    #pragma unroll
    for (int r = 0; r < BR; ++r) {
      const u16* gb = BT + bbase + (size_t)r * RROWS * K + k0;
      __builtin_amdgcn_global_load_lds((const GLOBAL_AS u32*)gb,
          (LDS_AS u32*)((u32*)Bs[buf] + r * 1024 + t * 4), 16, 0, 0);
    }
  };

  STAGE(0, 0);          // prologue: first tile in flight; drained by first sync
  int p = 0;
  for (int k0 = 0; k0 < K; k0 += BKT) {
    __syncthreads();    // drains vmcnt+lgkmcnt: staged(t) ready, reads(t-1) done
    if (k0 + BKT < K) STAGE(p ^ 1, k0 + BKT);  // uniform branch, no barrier inside

    if constexpr (BKT == 64) {
      #pragma unroll
      for (int s = 0; s < 2; ++s) {           // two 32-wide k-subtiles
        bf16x8 af[FM], bv[FN];
        #pragma unroll
        for (int i = 0; i < FM; ++i)
          af[i] = *(const bf16x8*)(As[p] + (wm + i * 16 + lrow) * 64 +
                                   (((s * 4 + quad) ^ (lrow & 7)) * 8));
        #pragma unroll
        for (int j = 0; j < FN; ++j)
          bv[j] = *(const bf16x8*)(Bs[p] + (wn + j * 16 + lrow) * 64 +
                                   (((s * 4 + quad) ^ (lrow & 7)) * 8));
        #pragma unroll
        for (int i = 0; i < FM; ++i)
          #pragma unroll
          for (int j = 0; j < FN; ++j)
            acc[i][j] = __builtin_amdgcn_mfma_f32_16x16x32_bf16(af[i], bv[j], acc[i][j], 0, 0, 0);
      }
    } else {
      bf16x8 af[FM], bv[FN];
      #pragma unroll
      for (int i = 0; i < FM; ++i)
        af[i] = *(const bf16x8*)(As[p] + (wm + i * 16 + lrow) * 32 + (quad ^ SWZ(lrow)) * 8);
      #pragma unroll
      for (int j = 0; j < FN; ++j)
        bv[j] = *(const bf16x8*)(Bs[p] + (wn + j * 16 + lrow) * 32 + (quad ^ SWZ(lrow)) * 8);
      #pragma unroll
      for (int i = 0; i < FM; ++i)
        #pragma unroll
        for (int j = 0; j < FN; ++j)
          acc[i][j] = __builtin_amdgcn_mfma_f32_16x16x32_bf16(af[i], bv[j], acc[i][j], 0, 0, 0);
    }
    p ^= 1;
  }

  // epilogue: C-layout col = lane&15, row = quad*4 + r
  #pragma unroll
  for (int i = 0; i < FM; ++i) {
    const int row0 = m0 + wm + i * 16 + quad * 4;
    float sc[4];
    if (EPI == 0) {
      #pragma unroll
      for (int r = 0; r < 4; ++r) sc[r] = rowscale[row0 + r];
    }
    #pragma unroll
    for (int j = 0; j < FN; ++j) {
      const int col = n0 + wn + j * 16 + lrow;
      const float bvs = bias[col];
      #pragma unroll
      for (int r = 0; r < 4; ++r) {
        float v = acc[i][j][r];
        if (EPI == 0) v = v * sc[r] + bvs;
        else v += bvs;
        if (EPI == 1) {
          const int cc = col & 255;  // N==256 here: flat idx = i16*16 + j16
          if ((cc & 15) <= (cc >> 4)) v = 0.f;  // keep strictly upper (j16 > i16)
        }
        const size_t idx = (size_t)(row0 + r) * N + col;
        if (OUTF32) ((float*)Cv)[idx] = v;
        else        ((u16*)Cv)[idx] = f2bf(v);
      }
    }
  }
}

// ---------------- per-row 16x16 expm via Taylor (exact: M nilpotent, M^16=0) ----------------
// One wave per row (4 rows/block). Left recurrence: term_k = (M * term_{k-1}) / k.
// Register-resident inner loop; see R0 notes. Primary: mfma_f32_16x16x16 (K=16,
// B-layout == C/D-layout -> free handoff). Fallback: 16x16x32 + 4 __shfl's.
#define HAS_MFMA16X16X16 __has_builtin(__builtin_amdgcn_mfma_f32_16x16x16bf16_1k)

__global__ __launch_bounds__(256) void expm_taylor(
    const u16* __restrict__ Mi, u16* __restrict__ Eo) {
  __shared__ u16 mbuf[4][256];
  const int t = threadIdx.x;
  const int w = t >> 6;
  const int lane = t & 63;
  const int q = lane >> 4;
  const int c = lane & 15;
  const size_t row = (size_t)blockIdx.x * 4 + w;

  *(uint2*)&mbuf[w][lane * 4] = *(const uint2*)(Mi + row * 256 + lane * 4);
  __syncthreads();  // once: make mbuf visible across lanes (cheap, outside loop)

  const u16* mb = mbuf[w];

  // res = I + M  (C-layout: entry (q*4+r, c))
  float res[4];
  #pragma unroll
  for (int r = 0; r < 4; ++r) {
    const int rw = q * 4 + r;
    res[r] = (rw == c ? 1.f : 0.f) + bf2f(mb[rw * 16 + c]);
  }

#if HAS_MFMA16X16X16
  bf16x4 afrM, bfr;
  #pragma unroll
  for (int jj = 0; jj < 4; ++jj) {
    afrM[jj] = (short)mb[c * 16 + q * 4 + jj];        // A[m=c][k=q*4+jj] = M[c][k]
    bfr[jj]  = (short)mb[(q * 4 + jj) * 16 + c];      // B[k][n=c] = term[k][c], term=M
  }
  #pragma unroll
  for (int k = 2; k <= 15; ++k) {
    const f32x4 z = {0.f, 0.f, 0.f, 0.f};
    f32x4 P = __builtin_amdgcn_mfma_f32_16x16x16bf16_1k(afrM, bfr, z, 0, 0, 0);
    const float inv = 1.0f / (float)k;
    #pragma unroll
    for (int r = 0; r < 4; ++r) {
      const float tv = P[r] * inv;
      res[r] += tv;
      bfr[r] = f2bf_s(tv);   // C(row=q*4+r,col=c) == B(k=q*4+r,n=c): free handoff
    }
  }
#else
  const bf16x8 z8 = {0, 0, 0, 0, 0, 0, 0, 0};
  bf16x8 afrM = z8;  // A[m=c][k=q*8+jj], zero-padded K 16->32 (q>=2)
  bf16x8 bfr  = z8;  // B[k=q*8+jj][n=c] = term[k][c], init term = M
  if (q < 2) {
    #pragma unroll
    for (int jj = 0; jj < 8; ++jj) {
      afrM[jj] = (short)mb[c * 16 + q * 8 + jj];
      bfr[jj]  = (short)mb[(q * 8 + jj) * 16 + c];
    }
  }
  const int qq = q & 1;
  const int sA = qq * 32 + c;       // lane holding term rows 8q..8q+3 (col c)
  const int sB = sA + 16;           // lane holding term rows 8q+4..8q+7
  #pragma unroll
  for (int k = 2; k <= 15; ++k) {
    const f32x4 z = {0.f, 0.f, 0.f, 0.f};
    f32x4 P = __builtin_amdgcn_mfma_f32_16x16x32_bf16(afrM, bfr, z, 0, 0, 0);
    const float inv = 1.0f / (float)k;
    float tv[4];
    #pragma unroll
    for (int r = 0; r < 4; ++r) { tv[r] = P[r] * inv; res[r] += tv[r]; }
    if (k < 15) {
      const u32 w0 = ((u32)f2bf(tv[0])) | (((u32)f2bf(tv[1])) << 16);
      const u32 w1 = ((u32)f2bf(tv[2])) | (((u32)f2bf(tv[3])) << 16);
      u32 a0 = (u32)__shfl((int)w0, sA, 64);
      u32 a1 = (u32)__shfl((int)w1, sA, 64);
      u32 a2 = (u32)__shfl((int)w0, sB, 64);
      u32 a3 = (u32)__shfl((int)w1, sB, 64);
      if (q >= 2) { a0 = a1 = a2 = a3 = 0; }  // K-pad rows stay zero
      union { u32 u[4]; bf16x8 v; } bu;
      bu.u[0] = a0; bu.u[1] = a1; bu.u[2] = a2; bu.u[3] = a3;
      bfr = bu.v;
    }
  }
#endif

  #pragma unroll
  for (int r = 0; r < 4; ++r)
    Eo[row * 256 + (size_t)(q * 4 + r) * 16 + c] = f2bf(res[r]);
}

extern "C" void kernel_launch(void* const* d_in, const int* in_sizes, int n_in,
                              void* d_out, int out_size, void* d_ws, size_t ws_size,
                              hipStream_t stream) {
  (void)in_sizes; (void)n_in; (void)out_size; (void)ws_size;
  // Inputs are FLOAT32 per the reference (jnp.float32).
  const float* x   = (const float*)d_in[0];
  const float* W_u = (const float*)d_in[1];
  const float* b_u = (const float*)d_in[2];
  const float* W_t = (const float*)d_in[3];
  const float* b_t = (const float*)d_in[4];
  const float* W_s = (const float*)d_in[5];
  const float* b_s = (const float*)d_in[6];
  float* out = (float*)d_out;  // output fp32 (reference output dtype)

  // d_out is 128 MiB (8192*4096 fp32) — dead until GEMM3; use it as scratch:
  //   xb     bf16[8192][4096] at +0      (64 MiB)
  //   latent bf16[8192][1024] at +64MiB  (16 MiB)
  //   mmat   bf16[8192][256]  at +80MiB  (4 MiB)
  u16* xb     = (u16*)d_out;
  u16* latent = xb + (size_t)8192 * 4096;
  u16* mmat   = latent + (size_t)8192 * 1024;

  char* ws = (char*)d_ws;  // ~14.5 MiB total
  size_t off = 0;
  float* sscale = (float*)(ws + off); off += (size_t)8192 * sizeof(float);
  u16* WuT  = (u16*)(ws + off); off += (size_t)1024 * 4096 * 2;  // 8 MiB
  u16* WtT  = (u16*)(ws + off); off += (size_t)256 * 1024 * 2;   // 0.5 MiB
  u16* WsT  = (u16*)(ws + off); off += (size_t)4096 * 256 * 2;   // 2 MiB
  u16* eexp = (u16*)(ws + off); off += (size_t)8192 * 256 * 2;   // 4 MiB

  // fused prologue: W_u/W_t/W_s transposes + RMS scales + x->bf16  (one dispatch)
  // blocks: 4096 (WuT) + 256 (WtT) + 1024 (WsT) + 8192 (rms rows) = 13568
  prologue_fused<<<13568, 256, 0, stream>>>(W_u, WuT, W_t, WtT, W_s, WsT,
                                            x, sscale, xb);

  // latent = diag(s)*(xb @ W_u) + b_u   [8192,1024] bf16
  // 128x128 tile, dbuf, BK=64 (R13): 64 barriers instead of 128
  gemm_bt<0, false, 4, 4, 64><<<dim3(1024 / 128, 8192 / 128), 256, 0, stream>>>(
      xb, WuT, b_u, sscale, latent, 8192, 1024, 4096);
  // mmat = mask(latent @ W_t + b_t)     [8192,256] bf16  (64x64 tile, BK=64)
  gemm_bt<1, false, 2, 2, 64><<<dim3(256 / 64, 8192 / 64), 256, 0, stream>>>(
      latent, WtT, b_t, nullptr, mmat, 8192, 256, 1024);
  // eexp = expm(mmat)                    [8192,256] bf16 (ws)
  expm_taylor<<<8192 / 4, 256, 0, stream>>>(mmat, eexp);
  // out = eexp @ W_s + b_s               [8192,4096] fp32
  // BK stays 32 here: GEMM3 runs 4 blocks/CU (32 KiB LDS); 64 KiB would halve it.
  gemm_bt<2, true, 4, 4, 32><<<dim3(4096 / 128, 8192 / 128), 256, 0, stream>>>(
      eexp, WsT, b_s, nullptr, out, 8192, 4096, 256);
}